// Round 1
// baseline (5983.216 us; speedup 1.0000x reference)
//
#include <hip/hip_runtime.h>

#define NN 50000
#define EE 800000

// ---------------------------------------------------------------------------
// Kernel 1: Qh/Kh/Vh = x @ W{Q,K,V}^T   (lane = node, W via scalar loads)
// ---------------------------------------------------------------------------
__global__ __launch_bounds__(256, 2) void qkv_kernel(
    const float* __restrict__ x,
    const float* __restrict__ WQ, const float* __restrict__ WK, const float* __restrict__ WV,
    float* __restrict__ Qh, float* __restrict__ Kh, float* __restrict__ Vh)
{
    int n = blockIdx.x * blockDim.x + threadIdx.x;
    bool act = (n < NN);
    int na = act ? n : 0;

    float xr[64];
    const float4* xv = (const float4*)(x + (size_t)na * 64);
    #pragma unroll
    for (int c = 0; c < 16; ++c) {
        float4 v = xv[c];
        xr[4*c+0] = v.x; xr[4*c+1] = v.y; xr[4*c+2] = v.z; xr[4*c+3] = v.w;
    }

    #pragma unroll 1
    for (int c = 0; c < 16; ++c) {
        float aq[4], ak[4], av[4];
        #pragma unroll
        for (int k = 0; k < 4; ++k) { aq[k] = 0.f; ak[k] = 0.f; av[k] = 0.f; }
        #pragma unroll
        for (int k = 0; k < 4; ++k) {
            const float* wq = WQ + (4*c + k) * 64;
            const float* wk = WK + (4*c + k) * 64;
            const float* wv = WV + (4*c + k) * 64;
            #pragma unroll
            for (int i = 0; i < 64; ++i) {
                aq[k] = fmaf(xr[i], wq[i], aq[k]);
                ak[k] = fmaf(xr[i], wk[i], ak[k]);
                av[k] = fmaf(xr[i], wv[i], av[k]);
            }
        }
        if (act) {
            *(float4*)(Qh + (size_t)n*64 + 4*c) = make_float4(aq[0], aq[1], aq[2], aq[3]);
            *(float4*)(Kh + (size_t)n*64 + 4*c) = make_float4(ak[0], ak[1], ak[2], ak[3]);
            *(float4*)(Vh + (size_t)n*64 + 4*c) = make_float4(av[0], av[1], av[2], av[3]);
        }
    }
}

// ---------------------------------------------------------------------------
// Kernel 2: fused per-edge pass (lane = edge)
//   Ew/Eb matvecs -> conn -> Eo (output) -> score/exp -> atomic scatter
// ---------------------------------------------------------------------------
__global__ __launch_bounds__(256, 2) void edge_kernel(
    const float* __restrict__ eattr, const int* __restrict__ eidx,
    const float* __restrict__ WEw, const float* __restrict__ WEb, const float* __restrict__ bEb,
    const float* __restrict__ WEo, const float* __restrict__ bEo, const float* __restrict__ Aw,
    const float* __restrict__ Qh, const float* __restrict__ Kh, const float* __restrict__ Vh,
    float* __restrict__ Eo_out, float* __restrict__ den,
    float* __restrict__ aggU, float* __restrict__ rowVU)
{
    int e = blockIdx.x * blockDim.x + threadIdx.x;   // EE divisible by 256
    int dst = eidx[e];
    int src = eidx[EE + e];

    // edge_attr row -> registers
    float ear[64];
    {
        const float4* v = (const float4*)(eattr + (size_t)e * 64);
        #pragma unroll
        for (int c = 0; c < 16; ++c) {
            float4 t = v[c];
            ear[4*c+0] = t.x; ear[4*c+1] = t.y; ear[4*c+2] = t.z; ear[4*c+3] = t.w;
        }
    }

    // conn = sign(qk*Ew)*sqrt(|qk*Ew|) + (Eb + bEb)
    float conn[64];
    {
        const float4* qv = (const float4*)(Qh + (size_t)dst * 64);
        const float4* kv = (const float4*)(Kh + (size_t)src * 64);
        #pragma unroll
        for (int c = 0; c < 16; ++c) {
            float4 q4 = qv[c], k4 = kv[c];
            float qk[4] = {q4.x + k4.x, q4.y + k4.y, q4.z + k4.z, q4.w + k4.w};
            #pragma unroll
            for (int k = 0; k < 4; ++k) {
                int j = 4*c + k;
                float ew = 0.f, ebv = 0.f;
                #pragma unroll
                for (int i = 0; i < 64; ++i) {
                    ew  = fmaf(ear[i], WEw[j*64 + i], ew);
                    ebv = fmaf(ear[i], WEb[j*64 + i], ebv);
                }
                ebv += bEb[j];
                float c1 = qk[k] * ew;
                float c2 = copysignf(sqrtf(fabsf(c1)), c1);
                conn[j] = c2 + ebv;
            }
        }
    }

    // score -> clamp -> exp (no max-subtraction needed: clamped to +-5)
    float ex[8];
    #pragma unroll
    for (int h = 0; h < 8; ++h) {
        float s = 0.f;
        #pragma unroll
        for (int d = 0; d < 8; ++d)
            s = fmaf(conn[h*8 + d], Aw[d*8 + h], s);   // Aw[D,H,1]
        s = fminf(fmaxf(s, -5.0f), 5.0f);
        float exv = __expf(s);
        ex[h] = exv;
        atomicAdd(den + (size_t)dst * 8 + h, exv);
    }

    // Eo = conn @ WEo^T + bEo  -> output ; rowVU += ex * Eo
    #pragma unroll
    for (int c = 0; c < 16; ++c) {
        float o[4];
        #pragma unroll
        for (int k = 0; k < 4; ++k) {
            int j = 4*c + k;
            float acc = bEo[j];
            #pragma unroll
            for (int i = 0; i < 64; ++i)
                acc = fmaf(conn[i], WEo[j*64 + i], acc);
            o[k] = acc;
        }
        *(float4*)(Eo_out + (size_t)e*64 + 4*c) = make_float4(o[0], o[1], o[2], o[3]);
        float exc = ex[c >> 1];   // h = (4c+k)/8 = c/2
        #pragma unroll
        for (int k = 0; k < 4; ++k)
            atomicAdd(rowVU + (size_t)dst*64 + 4*c + k, exc * o[k]);
    }

    // aggU += ex * Vh[src]
    {
        const float4* vv = (const float4*)(Vh + (size_t)src * 64);
        #pragma unroll
        for (int c = 0; c < 16; ++c) {
            float4 v4 = vv[c];
            float exc = ex[c >> 1];
            atomicAdd(aggU + (size_t)dst*64 + 4*c + 0, exc * v4.x);
            atomicAdd(aggU + (size_t)dst*64 + 4*c + 1, exc * v4.y);
            atomicAdd(aggU + (size_t)dst*64 + 4*c + 2, exc * v4.z);
            atomicAdd(aggU + (size_t)dst*64 + 4*c + 3, exc * v4.w);
        }
    }
}

// ---------------------------------------------------------------------------
// Kernel 3: h_out = (aggU + rowVU @ BW) / den     (thread = (n,h))
// ---------------------------------------------------------------------------
__global__ __launch_bounds__(256) void out_kernel(
    const float* __restrict__ aggU, const float* __restrict__ rowVU,
    const float* __restrict__ den, const float* __restrict__ BW,
    float* __restrict__ hout)
{
    int t = blockIdx.x * blockDim.x + threadIdx.x;
    if (t >= NN * 8) return;
    int n = t >> 3, h = t & 7;
    float dn = den[t];
    float inv = (dn > 0.f) ? (1.0f / dn) : 0.f;   // no-edge nodes -> 0 (matches ref)

    float rv[8];
    #pragma unroll
    for (int d = 0; d < 8; ++d) rv[d] = rowVU[(size_t)n*64 + h*8 + d];

    #pragma unroll
    for (int cc = 0; cc < 2; ++cc) {
        float o[4];
        #pragma unroll
        for (int k = 0; k < 4; ++k) {
            int c = 4*cc + k;
            float acc = aggU[(size_t)n*64 + h*8 + c];
            #pragma unroll
            for (int d = 0; d < 8; ++d)
                acc = fmaf(rv[d], BW[d*64 + h*8 + c], acc);   // BW[D,H,D]
            o[k] = acc * inv;
        }
        *(float4*)(hout + (size_t)n*64 + h*8 + 4*cc) = make_float4(o[0], o[1], o[2], o[3]);
    }
}

// ---------------------------------------------------------------------------
extern "C" void kernel_launch(void* const* d_in, const int* in_sizes, int n_in,
                              void* d_out, int out_size, void* d_ws, size_t ws_size,
                              hipStream_t stream)
{
    const float* x    = (const float*)d_in[0];
    const float* ea   = (const float*)d_in[1];
    const int*   eidx = (const int*)  d_in[2];
    const float* WQ   = (const float*)d_in[3];
    const float* WK   = (const float*)d_in[4];
    const float* WV   = (const float*)d_in[5];
    const float* WEw  = (const float*)d_in[6];
    const float* WEb  = (const float*)d_in[7];
    const float* bEb  = (const float*)d_in[8];
    const float* WEo  = (const float*)d_in[9];
    const float* bEo  = (const float*)d_in[10];
    const float* Aw   = (const float*)d_in[11];
    const float* BW   = (const float*)d_in[12];

    float* hout   = (float*)d_out;
    float* Eo_out = hout + (size_t)NN * 64;

    // workspace layout (floats): Qh | Kh | Vh | den | aggU | rowVU  (~65.6 MB)
    float* Qh    = (float*)d_ws;
    float* Kh    = Qh  + (size_t)NN * 64;
    float* Vh    = Kh  + (size_t)NN * 64;
    float* den   = Vh  + (size_t)NN * 64;
    float* aggU  = den + (size_t)NN * 8;
    float* rowVU = aggU + (size_t)NN * 64;

    // zero the accumulators (den, aggU, rowVU are contiguous)
    hipMemsetAsync(den, 0, (size_t)(NN*8 + NN*64 + NN*64) * sizeof(float), stream);

    qkv_kernel<<<(NN + 255) / 256, 256, 0, stream>>>(x, WQ, WK, WV, Qh, Kh, Vh);

    edge_kernel<<<EE / 256, 256, 0, stream>>>(ea, eidx, WEw, WEb, bEb, WEo, bEo, Aw,
                                              Qh, Kh, Vh, Eo_out, den, aggU, rowVU);

    out_kernel<<<(NN*8 + 255) / 256, 256, 0, stream>>>(aggU, rowVU, den, BW, hout);
}

// Round 2
// 1857.346 us; speedup vs baseline: 3.2214x; 3.2214x over previous
//
#include <hip/hip_runtime.h>

#define NN 50000
#define EE 800000

// ---------------------------------------------------------------------------
// Kernel 1: Qh/Kh/Vh = x @ W{Q,K,V}^T   (lane = node, W via scalar loads)
// ---------------------------------------------------------------------------
__global__ __launch_bounds__(256, 2) void qkv_kernel(
    const float* __restrict__ x,
    const float* __restrict__ WQ, const float* __restrict__ WK, const float* __restrict__ WV,
    float* __restrict__ Qh, float* __restrict__ Kh, float* __restrict__ Vh)
{
    int n = blockIdx.x * blockDim.x + threadIdx.x;
    bool act = (n < NN);
    int na = act ? n : 0;

    float xr[64];
    const float4* xv = (const float4*)(x + (size_t)na * 64);
    #pragma unroll
    for (int c = 0; c < 16; ++c) {
        float4 v = xv[c];
        xr[4*c+0] = v.x; xr[4*c+1] = v.y; xr[4*c+2] = v.z; xr[4*c+3] = v.w;
    }

    #pragma unroll 1
    for (int c = 0; c < 16; ++c) {
        float aq[4], ak[4], av[4];
        #pragma unroll
        for (int k = 0; k < 4; ++k) { aq[k] = 0.f; ak[k] = 0.f; av[k] = 0.f; }
        #pragma unroll
        for (int k = 0; k < 4; ++k) {
            const float* wq = WQ + (4*c + k) * 64;
            const float* wk = WK + (4*c + k) * 64;
            const float* wv = WV + (4*c + k) * 64;
            #pragma unroll
            for (int i = 0; i < 64; ++i) {
                aq[k] = fmaf(xr[i], wq[i], aq[k]);
                ak[k] = fmaf(xr[i], wk[i], ak[k]);
                av[k] = fmaf(xr[i], wv[i], av[k]);
            }
        }
        if (act) {
            *(float4*)(Qh + (size_t)n*64 + 4*c) = make_float4(aq[0], aq[1], aq[2], aq[3]);
            *(float4*)(Kh + (size_t)n*64 + 4*c) = make_float4(ak[0], ak[1], ak[2], ak[3]);
            *(float4*)(Vh + (size_t)n*64 + 4*c) = make_float4(av[0], av[1], av[2], av[3]);
        }
    }
}

// ---------------------------------------------------------------------------
// CSR build: histogram -> exclusive scan (single block) -> scatter
// ---------------------------------------------------------------------------
__global__ __launch_bounds__(256) void hist_kernel(const int* __restrict__ eidx,
                                                   int* __restrict__ cnt)
{
    int e = blockIdx.x * blockDim.x + threadIdx.x;   // EE % 256 == 0
    atomicAdd(&cnt[eidx[e]], 1);
}

__global__ __launch_bounds__(1024) void scan_kernel(const int* __restrict__ cnt,
                                                    int* __restrict__ rowstart,
                                                    int* __restrict__ cursor)
{
    __shared__ int buf[1024];
    __shared__ int carry;
    int tid = threadIdx.x;
    if (tid == 0) carry = 0;
    __syncthreads();
    for (int base = 0; base < NN; base += 1024) {
        int i = base + tid;
        int v = (i < NN) ? cnt[i] : 0;
        buf[tid] = v;
        __syncthreads();
        for (int off = 1; off < 1024; off <<= 1) {
            int t = (tid >= off) ? buf[tid - off] : 0;
            __syncthreads();
            buf[tid] += t;
            __syncthreads();
        }
        int excl = buf[tid] - v;
        if (i < NN) { int rs = carry + excl; rowstart[i] = rs; cursor[i] = rs; }
        __syncthreads();
        if (tid == 0) carry += buf[1023];
        __syncthreads();
    }
    if (tid == 0) rowstart[NN] = carry;
}

__global__ __launch_bounds__(256) void scatter_kernel(const int* __restrict__ eidx,
                                                      int* __restrict__ cursor,
                                                      int* __restrict__ perm,
                                                      int* __restrict__ psrc)
{
    int e = blockIdx.x * blockDim.x + threadIdx.x;
    int dst = eidx[e];
    int pos = atomicAdd(&cursor[dst], 1);
    perm[pos] = e;
    psrc[pos] = eidx[EE + e];
}

// ---------------------------------------------------------------------------
// Kernel 2: per-edge compute (lane = edge). No atomics.
//   Ew/Eb matvecs -> conn -> Eo (output #2) -> score/exp -> ex[E,8]
// ---------------------------------------------------------------------------
__global__ __launch_bounds__(256, 2) void edge_kernel(
    const float* __restrict__ eattr, const int* __restrict__ eidx,
    const float* __restrict__ WEw, const float* __restrict__ WEb, const float* __restrict__ bEb,
    const float* __restrict__ WEo, const float* __restrict__ bEo, const float* __restrict__ Aw,
    const float* __restrict__ Qh, const float* __restrict__ Kh,
    float* __restrict__ Eo_out, float* __restrict__ exbuf)
{
    int e = blockIdx.x * blockDim.x + threadIdx.x;   // EE divisible by 256
    int dst = eidx[e];
    int src = eidx[EE + e];

    // edge_attr row -> registers
    float ear[64];
    {
        const float4* v = (const float4*)(eattr + (size_t)e * 64);
        #pragma unroll
        for (int c = 0; c < 16; ++c) {
            float4 t = v[c];
            ear[4*c+0] = t.x; ear[4*c+1] = t.y; ear[4*c+2] = t.z; ear[4*c+3] = t.w;
        }
    }

    // conn = sign(qk*Ew)*sqrt(|qk*Ew|) + (Eb + bEb)
    float conn[64];
    {
        const float4* qv = (const float4*)(Qh + (size_t)dst * 64);
        const float4* kv = (const float4*)(Kh + (size_t)src * 64);
        #pragma unroll
        for (int c = 0; c < 16; ++c) {
            float4 q4 = qv[c], k4 = kv[c];
            float qk[4] = {q4.x + k4.x, q4.y + k4.y, q4.z + k4.z, q4.w + k4.w};
            #pragma unroll
            for (int k = 0; k < 4; ++k) {
                int j = 4*c + k;
                float ew = 0.f, ebv = 0.f;
                #pragma unroll
                for (int i = 0; i < 64; ++i) {
                    ew  = fmaf(ear[i], WEw[j*64 + i], ew);
                    ebv = fmaf(ear[i], WEb[j*64 + i], ebv);
                }
                ebv += bEb[j];
                float c1 = qk[k] * ew;
                float c2 = copysignf(sqrtf(fabsf(c1)), c1);
                conn[j] = c2 + ebv;
            }
        }
    }

    // score -> clamp -> exp (clamped to +-5, so no segment-max needed)
    float ex[8];
    #pragma unroll
    for (int h = 0; h < 8; ++h) {
        float s = 0.f;
        #pragma unroll
        for (int d = 0; d < 8; ++d)
            s = fmaf(conn[h*8 + d], Aw[d*8 + h], s);   // Aw[D,H,1]
        s = fminf(fmaxf(s, -5.0f), 5.0f);
        ex[h] = __expf(s);
    }
    *(float4*)(exbuf + (size_t)e*8 + 0) = make_float4(ex[0], ex[1], ex[2], ex[3]);
    *(float4*)(exbuf + (size_t)e*8 + 4) = make_float4(ex[4], ex[5], ex[6], ex[7]);

    // Eo = conn @ WEo^T + bEo  -> output
    #pragma unroll
    for (int c = 0; c < 16; ++c) {
        float o[4];
        #pragma unroll
        for (int k = 0; k < 4; ++k) {
            int j = 4*c + k;
            float acc = bEo[j];
            #pragma unroll
            for (int i = 0; i < 64; ++i)
                acc = fmaf(conn[i], WEo[j*64 + i], acc);
            o[k] = acc;
        }
        *(float4*)(Eo_out + (size_t)e*64 + 4*c) = make_float4(o[0], o[1], o[2], o[3]);
    }
}

// ---------------------------------------------------------------------------
// Kernel 3: node aggregation. One wave per node; lane = (h,d).
//   agg/rowV/den in registers over the node's CSR edge list, then BW einsum
//   via __shfl and divide by den.
// ---------------------------------------------------------------------------
__global__ __launch_bounds__(256) void node_kernel(
    const int* __restrict__ rowstart, const int* __restrict__ perm,
    const int* __restrict__ psrc,
    const float* __restrict__ exbuf, const float* __restrict__ Eo,
    const float* __restrict__ Vh, const float* __restrict__ BW,
    float* __restrict__ hout)
{
    int n = (blockIdx.x * blockDim.x + threadIdx.x) >> 6;   // NN*64 % 256 == 0
    int lane = threadIdx.x & 63;
    int h = lane >> 3, d = lane & 7;

    int beg = rowstart[n], end = rowstart[n + 1];
    float agg = 0.f, rv = 0.f, den = 0.f;
    for (int j = beg; j < end; ++j) {
        int e   = perm[j];
        int src = psrc[j];
        float exv = exbuf[(size_t)e*8 + h];
        agg = fmaf(exv, Vh[(size_t)src*64 + lane], agg);
        rv  = fmaf(exv, Eo[(size_t)e*64 + lane], rv);
        den += exv;
    }
    float inv = (den > 0.f) ? (1.0f / den) : 0.f;

    // out[n,h,d] = (agg + sum_dd rowV[n,h,dd] * BW[dd,h,d]) / den
    float acc = agg;
    #pragma unroll
    for (int dd = 0; dd < 8; ++dd) {
        float rvd = __shfl(rv, (h << 3) + dd, 64);
        acc = fmaf(rvd, BW[dd*64 + (h << 3) + d], acc);
    }
    hout[(size_t)n*64 + lane] = acc * inv;
}

// ---------------------------------------------------------------------------
extern "C" void kernel_launch(void* const* d_in, const int* in_sizes, int n_in,
                              void* d_out, int out_size, void* d_ws, size_t ws_size,
                              hipStream_t stream)
{
    const float* x    = (const float*)d_in[0];
    const float* ea   = (const float*)d_in[1];
    const int*   eidx = (const int*)  d_in[2];
    const float* WQ   = (const float*)d_in[3];
    const float* WK   = (const float*)d_in[4];
    const float* WV   = (const float*)d_in[5];
    const float* WEw  = (const float*)d_in[6];
    const float* WEb  = (const float*)d_in[7];
    const float* bEb  = (const float*)d_in[8];
    const float* WEo  = (const float*)d_in[9];
    const float* bEo  = (const float*)d_in[10];
    const float* Aw   = (const float*)d_in[11];
    const float* BW   = (const float*)d_in[12];

    float* hout   = (float*)d_out;
    float* Eo_out = hout + (size_t)NN * 64;

    // workspace layout: Qh | Kh | Vh | exbuf | cnt | rowstart | cursor | perm | psrc
    float* Qh    = (float*)d_ws;
    float* Kh    = Qh + (size_t)NN * 64;
    float* Vh    = Kh + (size_t)NN * 64;
    float* exbuf = Vh + (size_t)NN * 64;
    int* cnt      = (int*)(exbuf + (size_t)EE * 8);
    int* rowstart = cnt + NN;
    int* cursor   = rowstart + (NN + 1);
    int* perm     = cursor + NN;
    int* psrc     = perm + EE;

    hipMemsetAsync(cnt, 0, (size_t)NN * sizeof(int), stream);

    hist_kernel<<<EE / 256, 256, 0, stream>>>(eidx, cnt);
    scan_kernel<<<1, 1024, 0, stream>>>(cnt, rowstart, cursor);
    scatter_kernel<<<EE / 256, 256, 0, stream>>>(eidx, cursor, perm, psrc);

    qkv_kernel<<<(NN + 255) / 256, 256, 0, stream>>>(x, WQ, WK, WV, Qh, Kh, Vh);

    edge_kernel<<<EE / 256, 256, 0, stream>>>(ea, eidx, WEw, WEb, bEb, WEo, bEo, Aw,
                                              Qh, Kh, Eo_out, exbuf);

    node_kernel<<<(NN * 64) / 256, 256, 0, stream>>>(rowstart, perm, psrc,
                                                     exbuf, Eo_out, Vh, BW, hout);
}

// Round 3
// 491.233 us; speedup vs baseline: 12.1800x; 3.7810x over previous
//
#include <hip/hip_runtime.h>

#define NN 50000
#define EE 800000

typedef __attribute__((ext_vector_type(8))) short short8;
typedef __attribute__((ext_vector_type(16))) float f32x16;

static __device__ __forceinline__ unsigned short f2bf(float f) {
    unsigned u = __float_as_uint(f);
    u += 0x7fffu + ((u >> 16) & 1u);
    return (unsigned short)(u >> 16);
}
static __device__ __forceinline__ unsigned pack2(float a, float b) {
    return (unsigned)f2bf(a) | ((unsigned)f2bf(b) << 16);
}
static __device__ __forceinline__ float bf2f(unsigned short s) {
    return __uint_as_float((unsigned)s << 16);
}
static __device__ __forceinline__ f32x16 splat16(float v) {
    f32x16 r;
    #pragma unroll
    for (int i = 0; i < 16; ++i) r[i] = v;
    return r;
}

union U8 { short8 v; uint2 u[2]; };

// read an 8-bf16 MFMA fragment: elems [0..3] at k0, [4..7] at k0+8 (K-half concat model)
static __device__ __forceinline__ short8 ldsfrag(const unsigned short* rowbase, int k0) {
    U8 t;
    t.u[0] = *(const uint2*)(rowbase + k0);
    t.u[1] = *(const uint2*)(rowbase + k0 + 8);
    return t.v;
}

// ---------------------------------------------------------------------------
// Kernel 1: Qh/Kh/Vh via MFMA. Block = 256 thr = 4 waves x 32 rows.
// ---------------------------------------------------------------------------
__global__ __launch_bounds__(256) void qkv_mfma_kernel(
    const float* __restrict__ x,
    const float* __restrict__ WQ, const float* __restrict__ WK, const float* __restrict__ WV,
    float* __restrict__ Qh, float* __restrict__ Kh, float* __restrict__ Vh)
{
    __shared__ unsigned short s_wq[64][68];
    __shared__ unsigned short s_wk[64][68];
    __shared__ unsigned short s_wv[64][68];

    int tid = threadIdx.x;
    #pragma unroll
    for (int t = 0; t < 16; ++t) {
        int idx = t * 256 + tid;
        int r = idx >> 6, c = idx & 63;
        s_wq[r][c] = f2bf(WQ[idx]);
        s_wk[r][c] = f2bf(WK[idx]);
        s_wv[r][c] = f2bf(WV[idx]);
    }
    __syncthreads();

    int wid = tid >> 6, lane = tid & 63;
    int m0 = blockIdx.x * 128 + wid * 32;
    int lo5 = lane & 31, hi = lane >> 5;

    int rowi = m0 + lo5;
    const float* arow = x + (size_t)(rowi < NN ? rowi : NN - 1) * 64;
    short8 af[4];
    #pragma unroll
    for (int ks = 0; ks < 4; ++ks) {
        int k0 = ks * 16 + hi * 4;
        float4 a0 = *(const float4*)(arow + k0);
        float4 a1 = *(const float4*)(arow + k0 + 8);
        U8 t;
        t.u[0] = make_uint2(pack2(a0.x, a0.y), pack2(a0.z, a0.w));
        t.u[1] = make_uint2(pack2(a1.x, a1.y), pack2(a1.z, a1.w));
        af[ks] = t.v;
    }

    #pragma unroll
    for (int nt = 0; nt < 2; ++nt) {
        int n = nt * 32 + lo5;
        f32x16 cQ = splat16(0.f), cK = splat16(0.f), cV = splat16(0.f);
        #pragma unroll
        for (int ks = 0; ks < 4; ++ks) {
            int k0 = ks * 16 + hi * 4;
            cQ = __builtin_amdgcn_mfma_f32_32x32x16_bf16(af[ks], ldsfrag(s_wq[n], k0), cQ, 0, 0, 0);
            cK = __builtin_amdgcn_mfma_f32_32x32x16_bf16(af[ks], ldsfrag(s_wk[n], k0), cK, 0, 0, 0);
            cV = __builtin_amdgcn_mfma_f32_32x32x16_bf16(af[ks], ldsfrag(s_wv[n], k0), cV, 0, 0, 0);
        }
        #pragma unroll
        for (int r = 0; r < 16; ++r) {
            int m = (r & 3) + 8 * (r >> 2) + 4 * hi;
            int gm = m0 + m;
            if (gm < NN) {
                Qh[(size_t)gm * 64 + n] = cQ[r];
                Kh[(size_t)gm * 64 + n] = cK[r];
                Vh[(size_t)gm * 64 + n] = cV[r];
            }
        }
    }
}

// ---------------------------------------------------------------------------
// CSR build: histogram -> exclusive scan (single block) -> scatter
// ---------------------------------------------------------------------------
__global__ __launch_bounds__(256) void hist_kernel(const int* __restrict__ eidx,
                                                   int* __restrict__ cnt)
{
    int e = blockIdx.x * blockDim.x + threadIdx.x;
    atomicAdd(&cnt[eidx[e]], 1);
}

__global__ __launch_bounds__(1024) void scan_kernel(const int* __restrict__ cnt,
                                                    int* __restrict__ rowstart,
                                                    int* __restrict__ cursor)
{
    __shared__ int buf[1024];
    __shared__ int carry;
    int tid = threadIdx.x;
    if (tid == 0) carry = 0;
    __syncthreads();
    for (int base = 0; base < NN; base += 1024) {
        int i = base + tid;
        int v = (i < NN) ? cnt[i] : 0;
        buf[tid] = v;
        __syncthreads();
        for (int off = 1; off < 1024; off <<= 1) {
            int t = (tid >= off) ? buf[tid - off] : 0;
            __syncthreads();
            buf[tid] += t;
            __syncthreads();
        }
        int excl = buf[tid] - v;
        if (i < NN) { int rs = carry + excl; rowstart[i] = rs; cursor[i] = rs; }
        __syncthreads();
        if (tid == 0) carry += buf[1023];
        __syncthreads();
    }
    if (tid == 0) rowstart[NN] = carry;
}

__global__ __launch_bounds__(256) void scatter_kernel(const int* __restrict__ eidx,
                                                      int* __restrict__ cursor,
                                                      int* __restrict__ perm,
                                                      int* __restrict__ psrc)
{
    int e = blockIdx.x * blockDim.x + threadIdx.x;
    int dst = eidx[e];
    int pos = atomicAdd(&cursor[dst], 1);
    perm[pos] = e;
    psrc[pos] = eidx[EE + e];
}

// ---------------------------------------------------------------------------
// Kernel 2: per-edge MFMA pass. Block = 256 thr = 4 waves x 32 edges.
//   Ew/Eb GEMM -> conn (LDS) -> score GEMM (Aw block-diag) -> ex -> Eo GEMM
// ---------------------------------------------------------------------------
__global__ __launch_bounds__(256) void edge_mfma_kernel(
    const float* __restrict__ eattr, const int* __restrict__ eidx,
    const float* __restrict__ WEw, const float* __restrict__ WEb, const float* __restrict__ bEb,
    const float* __restrict__ WEo, const float* __restrict__ bEo, const float* __restrict__ Aw,
    const float* __restrict__ Qh, const float* __restrict__ Kh,
    float* __restrict__ Eo_out, float* __restrict__ exbuf)
{
    __shared__ unsigned short s_wew[64][68];
    __shared__ unsigned short s_web[64][68];
    __shared__ unsigned short s_weo[64][68];
    __shared__ unsigned short s_baw[32][68];      // B_aw^T: [n=h][k], block-diagonal Aw
    __shared__ unsigned short s_qk[4][32][68];    // per-wave qk (bf16)
    __shared__ unsigned short s_conn[4][32][68];  // per-wave conn (bf16)

    int tid = threadIdx.x;
    #pragma unroll
    for (int t = 0; t < 16; ++t) {
        int idx = t * 256 + tid;
        int r = idx >> 6, c = idx & 63;
        s_wew[r][c] = f2bf(WEw[idx]);
        s_web[r][c] = f2bf(WEb[idx]);
        s_weo[r][c] = f2bf(WEo[idx]);
    }
    #pragma unroll
    for (int t = 0; t < 8; ++t) {
        int idx = t * 256 + tid;
        int n = idx >> 6, k = idx & 63;
        s_baw[n][k] = (n == (k >> 3)) ? f2bf(Aw[(k & 7) * 8 + n]) : (unsigned short)0;
    }
    __syncthreads();

    int wid = tid >> 6, lane = tid & 63;
    int e0 = blockIdx.x * 128 + wid * 32;
    int lo5 = lane & 31, hi = lane >> 5;

    // gather qk = Qh[dst]+Kh[src] -> s_qk[wid]  (coalesced float4, bf16 store)
    {
        int mm = lane >> 4;         // 0..3
        int cc = (lane & 15) * 4;   // 0..60
        #pragma unroll
        for (int t = 0; t < 8; ++t) {
            int m = t * 4 + mm;
            int e = e0 + m;
            int dst = eidx[e], src = eidx[EE + e];
            float4 q = *(const float4*)(Qh + (size_t)dst * 64 + cc);
            float4 k = *(const float4*)(Kh + (size_t)src * 64 + cc);
            *(uint2*)&s_qk[wid][m][cc] = make_uint2(pack2(q.x + k.x, q.y + k.y),
                                                    pack2(q.z + k.z, q.w + k.w));
        }
    }

    // eattr A-fragments (4 K-steps)
    short8 af[4];
    {
        const float* arow = eattr + (size_t)(e0 + lo5) * 64;
        #pragma unroll
        for (int ks = 0; ks < 4; ++ks) {
            int k0 = ks * 16 + hi * 4;
            float4 a0 = *(const float4*)(arow + k0);
            float4 a1 = *(const float4*)(arow + k0 + 8);
            U8 t;
            t.u[0] = make_uint2(pack2(a0.x, a0.y), pack2(a0.z, a0.w));
            t.u[1] = make_uint2(pack2(a1.x, a1.y), pack2(a1.z, a1.w));
            af[ks] = t.v;
        }
    }

    // Ew/Eb GEMM + conn, per 32-col tile
    #pragma unroll
    for (int nt = 0; nt < 2; ++nt) {
        int n = nt * 32 + lo5;
        f32x16 cEw = splat16(0.f), cEb = splat16(0.f);
        #pragma unroll
        for (int ks = 0; ks < 4; ++ks) {
            int k0 = ks * 16 + hi * 4;
            cEw = __builtin_amdgcn_mfma_f32_32x32x16_bf16(af[ks], ldsfrag(s_wew[n], k0), cEw, 0, 0, 0);
            cEb = __builtin_amdgcn_mfma_f32_32x32x16_bf16(af[ks], ldsfrag(s_web[n], k0), cEb, 0, 0, 0);
        }
        float bEbn = bEb[n];
        #pragma unroll
        for (int r = 0; r < 16; ++r) {
            int m = (r & 3) + 8 * (r >> 2) + 4 * hi;
            float qk = bf2f(s_qk[wid][m][n]);
            float c1 = qk * cEw[r];
            float c2 = copysignf(sqrtf(fabsf(c1)), c1);
            s_conn[wid][m][n] = f2bf(c2 + cEb[r] + bEbn);
        }
    }

    // conn A-fragments
    short8 ca[4];
    #pragma unroll
    for (int ks = 0; ks < 4; ++ks) {
        int k0 = ks * 16 + hi * 4;
        ca[ks] = ldsfrag(s_conn[wid][lo5], k0);
    }

    // score GEMM against block-diagonal Aw -> ex -> exbuf
    {
        f32x16 cS = splat16(0.f);
        #pragma unroll
        for (int ks = 0; ks < 4; ++ks) {
            int k0 = ks * 16 + hi * 4;
            cS = __builtin_amdgcn_mfma_f32_32x32x16_bf16(ca[ks], ldsfrag(s_baw[lo5], k0), cS, 0, 0, 0);
        }
        if (lo5 < 8) {
            #pragma unroll
            for (int r = 0; r < 16; ++r) {
                int m = (r & 3) + 8 * (r >> 2) + 4 * hi;
                float s = fminf(fmaxf(cS[r], -5.0f), 5.0f);
                exbuf[(size_t)(e0 + m) * 8 + lo5] = __expf(s);
            }
        }
    }

    // Eo GEMM (+bias) -> global (coalesced full-line stores)
    #pragma unroll
    for (int nt = 0; nt < 2; ++nt) {
        int n = nt * 32 + lo5;
        f32x16 cO = splat16(bEo[n]);
        #pragma unroll
        for (int ks = 0; ks < 4; ++ks) {
            int k0 = ks * 16 + hi * 4;
            cO = __builtin_amdgcn_mfma_f32_32x32x16_bf16(ca[ks], ldsfrag(s_weo[n], k0), cO, 0, 0, 0);
        }
        #pragma unroll
        for (int r = 0; r < 16; ++r) {
            int m = (r & 3) + 8 * (r >> 2) + 4 * hi;
            Eo_out[(size_t)(e0 + m) * 64 + n] = cO[r];
        }
    }
}

// ---------------------------------------------------------------------------
// Kernel 3: node aggregation (CSR). One wave per node; lane = (h,d).
// ---------------------------------------------------------------------------
__global__ __launch_bounds__(256) void node_kernel(
    const int* __restrict__ rowstart, const int* __restrict__ perm,
    const int* __restrict__ psrc,
    const float* __restrict__ exbuf, const float* __restrict__ Eo,
    const float* __restrict__ Vh, const float* __restrict__ BW,
    float* __restrict__ hout)
{
    int n = (blockIdx.x * blockDim.x + threadIdx.x) >> 6;
    int lane = threadIdx.x & 63;
    int h = lane >> 3, d = lane & 7;

    int beg = rowstart[n], end = rowstart[n + 1];
    float agg = 0.f, rv = 0.f, den = 0.f;
    for (int j = beg; j < end; ++j) {
        int e   = perm[j];
        int src = psrc[j];
        float exv = exbuf[(size_t)e * 8 + h];
        agg = fmaf(exv, Vh[(size_t)src * 64 + lane], agg);
        rv  = fmaf(exv, Eo[(size_t)e * 64 + lane], rv);
        den += exv;
    }
    float inv = (den > 0.f) ? (1.0f / den) : 0.f;

    float acc = agg;
    #pragma unroll
    for (int dd = 0; dd < 8; ++dd) {
        float rvd = __shfl(rv, (h << 3) + dd, 64);
        acc = fmaf(rvd, BW[dd * 64 + (h << 3) + d], acc);
    }
    hout[(size_t)n * 64 + lane] = acc * inv;
}

// ---------------------------------------------------------------------------
extern "C" void kernel_launch(void* const* d_in, const int* in_sizes, int n_in,
                              void* d_out, int out_size, void* d_ws, size_t ws_size,
                              hipStream_t stream)
{
    const float* x    = (const float*)d_in[0];
    const float* ea   = (const float*)d_in[1];
    const int*   eidx = (const int*)  d_in[2];
    const float* WQ   = (const float*)d_in[3];
    const float* WK   = (const float*)d_in[4];
    const float* WV   = (const float*)d_in[5];
    const float* WEw  = (const float*)d_in[6];
    const float* WEb  = (const float*)d_in[7];
    const float* bEb  = (const float*)d_in[8];
    const float* WEo  = (const float*)d_in[9];
    const float* bEo  = (const float*)d_in[10];
    const float* Aw   = (const float*)d_in[11];
    const float* BW   = (const float*)d_in[12];

    float* hout   = (float*)d_out;
    float* Eo_out = hout + (size_t)NN * 64;

    float* Qh    = (float*)d_ws;
    float* Kh    = Qh + (size_t)NN * 64;
    float* Vh    = Kh + (size_t)NN * 64;
    float* exbuf = Vh + (size_t)NN * 64;
    int* cnt      = (int*)(exbuf + (size_t)EE * 8);
    int* rowstart = cnt + NN;
    int* cursor   = rowstart + (NN + 1);
    int* perm     = cursor + NN;
    int* psrc     = perm + EE;

    hipMemsetAsync(cnt, 0, (size_t)NN * sizeof(int), stream);

    hist_kernel<<<EE / 256, 256, 0, stream>>>(eidx, cnt);
    scan_kernel<<<1, 1024, 0, stream>>>(cnt, rowstart, cursor);
    scatter_kernel<<<EE / 256, 256, 0, stream>>>(eidx, cursor, perm, psrc);

    qkv_mfma_kernel<<<(NN + 127) / 128, 256, 0, stream>>>(x, WQ, WK, WV, Qh, Kh, Vh);

    edge_mfma_kernel<<<EE / 128, 256, 0, stream>>>(ea, eidx, WEw, WEb, bEb, WEo, bEo, Aw,
                                                   Qh, Kh, Eo_out, exbuf);

    node_kernel<<<(NN * 64) / 256, 256, 0, stream>>>(rowstart, perm, psrc,
                                                     exbuf, Eo_out, Vh, BW, hout);
}

// Round 4
// 364.887 us; speedup vs baseline: 16.3974x; 1.3463x over previous
//
#include <hip/hip_runtime.h>

#define NN 50000
#define EE 800000
#define NTILES (EE / 128)
#define NB ((NN + 1023) / 1024)

typedef __attribute__((ext_vector_type(8))) short short8;
typedef __attribute__((ext_vector_type(16))) float f32x16;

static __device__ __forceinline__ unsigned short f2bf(float f) {
    unsigned u = __float_as_uint(f);
    u += 0x7fffu + ((u >> 16) & 1u);
    return (unsigned short)(u >> 16);
}
static __device__ __forceinline__ unsigned pack2(float a, float b) {
    return (unsigned)f2bf(a) | ((unsigned)f2bf(b) << 16);
}
static __device__ __forceinline__ float bf2f(unsigned short s) {
    return __uint_as_float((unsigned)s << 16);
}
static __device__ __forceinline__ f32x16 splat16(float v) {
    f32x16 r;
    #pragma unroll
    for (int i = 0; i < 16; ++i) r[i] = v;
    return r;
}

union U8 { short8 v; uint2 u[2]; };

// read an 8-bf16 MFMA fragment: elems [0..3] at k0, [4..7] at k0+8
static __device__ __forceinline__ short8 ldsfrag(const unsigned short* rowbase, int k0) {
    U8 t;
    t.u[0] = *(const uint2*)(rowbase + k0);
    t.u[1] = *(const uint2*)(rowbase + k0 + 8);
    return t.v;
}

// ---------------------------------------------------------------------------
// Kernel 1: Qh/Kh/Vh via MFMA. Block = 256 thr = 4 waves x 32 rows.
// ---------------------------------------------------------------------------
__global__ __launch_bounds__(256) void qkv_mfma_kernel(
    const float* __restrict__ x,
    const float* __restrict__ WQ, const float* __restrict__ WK, const float* __restrict__ WV,
    float* __restrict__ Qh, float* __restrict__ Kh, float* __restrict__ Vh)
{
    __shared__ unsigned short s_wq[64][68];
    __shared__ unsigned short s_wk[64][68];
    __shared__ unsigned short s_wv[64][68];

    int tid = threadIdx.x;
    #pragma unroll
    for (int t = 0; t < 16; ++t) {
        int idx = t * 256 + tid;
        int r = idx >> 6, c = idx & 63;
        s_wq[r][c] = f2bf(WQ[idx]);
        s_wk[r][c] = f2bf(WK[idx]);
        s_wv[r][c] = f2bf(WV[idx]);
    }
    __syncthreads();

    int wid = tid >> 6, lane = tid & 63;
    int m0 = blockIdx.x * 128 + wid * 32;
    int lo5 = lane & 31, hi = lane >> 5;

    int rowi = m0 + lo5;
    const float* arow = x + (size_t)(rowi < NN ? rowi : NN - 1) * 64;
    short8 af[4];
    #pragma unroll
    for (int ks = 0; ks < 4; ++ks) {
        int k0 = ks * 16 + hi * 4;
        float4 a0 = *(const float4*)(arow + k0);
        float4 a1 = *(const float4*)(arow + k0 + 8);
        U8 t;
        t.u[0] = make_uint2(pack2(a0.x, a0.y), pack2(a0.z, a0.w));
        t.u[1] = make_uint2(pack2(a1.x, a1.y), pack2(a1.z, a1.w));
        af[ks] = t.v;
    }

    #pragma unroll
    for (int nt = 0; nt < 2; ++nt) {
        int n = nt * 32 + lo5;
        f32x16 cQ = splat16(0.f), cK = splat16(0.f), cV = splat16(0.f);
        #pragma unroll
        for (int ks = 0; ks < 4; ++ks) {
            int k0 = ks * 16 + hi * 4;
            cQ = __builtin_amdgcn_mfma_f32_32x32x16_bf16(af[ks], ldsfrag(s_wq[n], k0), cQ, 0, 0, 0);
            cK = __builtin_amdgcn_mfma_f32_32x32x16_bf16(af[ks], ldsfrag(s_wk[n], k0), cK, 0, 0, 0);
            cV = __builtin_amdgcn_mfma_f32_32x32x16_bf16(af[ks], ldsfrag(s_wv[n], k0), cV, 0, 0, 0);
        }
        #pragma unroll
        for (int r = 0; r < 16; ++r) {
            int m = (r & 3) + 8 * (r >> 2) + 4 * hi;
            int gm = m0 + m;
            if (gm < NN) {
                Qh[(size_t)gm * 64 + n] = cQ[r];
                Kh[(size_t)gm * 64 + n] = cK[r];
                Vh[(size_t)gm * 64 + n] = cV[r];
            }
        }
    }
}

// ---------------------------------------------------------------------------
// CSR build: histogram -> hierarchical scan -> scatter (with inverse perm)
// ---------------------------------------------------------------------------
__global__ __launch_bounds__(256) void hist_kernel(const int* __restrict__ eidx,
                                                   int* __restrict__ cnt)
{
    int e = blockIdx.x * blockDim.x + threadIdx.x;
    atomicAdd(&cnt[eidx[e]], 1);
}

__global__ __launch_bounds__(1024) void scan1_kernel(const int* __restrict__ cnt,
                                                     int* __restrict__ rowstart,
                                                     int* __restrict__ bsum)
{
    __shared__ int buf[1024];
    int tid = threadIdx.x;
    int i = blockIdx.x * 1024 + tid;
    int v = (i < NN) ? cnt[i] : 0;
    buf[tid] = v;
    __syncthreads();
    for (int off = 1; off < 1024; off <<= 1) {
        int t = (tid >= off) ? buf[tid - off] : 0;
        __syncthreads();
        buf[tid] += t;
        __syncthreads();
    }
    if (i < NN) rowstart[i] = buf[tid] - v;       // local exclusive prefix
    if (tid == 1023) bsum[blockIdx.x] = buf[1023]; // block total
}

__global__ __launch_bounds__(64) void scan2_kernel(const int* __restrict__ bsum,
                                                   int* __restrict__ boff,
                                                   int* __restrict__ rowstart)
{
    int lane = threadIdx.x;
    int v = (lane < NB) ? bsum[lane] : 0;
    int s = v;
    #pragma unroll
    for (int off = 1; off < 64; off <<= 1) {
        int t = __shfl_up(s, off, 64);
        if (lane >= off) s += t;
    }
    if (lane < NB) boff[lane] = s - v;
    if (lane == 63) rowstart[NN] = s;
}

__global__ __launch_bounds__(1024) void scan3_kernel(int* __restrict__ rowstart,
                                                     const int* __restrict__ boff,
                                                     int* __restrict__ cursor)
{
    int i = blockIdx.x * 1024 + threadIdx.x;
    if (i < NN) {
        int r = rowstart[i] + boff[blockIdx.x];
        rowstart[i] = r;
        cursor[i] = r;
    }
}

__global__ __launch_bounds__(256) void scatter_kernel(const int* __restrict__ eidx,
                                                      int* __restrict__ cursor,
                                                      int* __restrict__ perm,
                                                      int* __restrict__ psrc,
                                                      int* __restrict__ inv)
{
    int e = blockIdx.x * blockDim.x + threadIdx.x;
    int dst = eidx[e];
    int pos = atomicAdd(&cursor[dst], 1);
    perm[pos] = e;
    psrc[pos] = eidx[EE + e];
    inv[e] = pos;
}

// ---------------------------------------------------------------------------
// Kernel 2: per-edge MFMA pass. 4 waves x 32 edges, grid-stride over tiles.
//   LDS: 3 weight tiles + one shared qk/conn buffer per wave (43.5 KB ->
//   3 blocks/CU). Score on VALU from A-fragments (no score MFMA, no s_baw).
// ---------------------------------------------------------------------------
__global__ __launch_bounds__(256) void edge_mfma_kernel(
    const float* __restrict__ eattr, const int* __restrict__ eidx,
    const int* __restrict__ inv,
    const float* __restrict__ WEw, const float* __restrict__ WEb, const float* __restrict__ bEb,
    const float* __restrict__ WEo, const float* __restrict__ bEo, const float* __restrict__ Aw,
    const float* __restrict__ Qh, const float* __restrict__ Kh,
    float* __restrict__ Eo_out, float* __restrict__ exbuf)
{
    __shared__ unsigned short s_wew[64][68];
    __shared__ unsigned short s_web[64][68];
    __shared__ unsigned short s_weo[64][68];
    __shared__ unsigned short s_cq[4][32][68];   // qk then conn (same slots)

    int tid = threadIdx.x;
    #pragma unroll
    for (int t = 0; t < 16; ++t) {
        int idx = t * 256 + tid;
        int r = idx >> 6, c = idx & 63;
        s_wew[r][c] = f2bf(WEw[idx]);
        s_web[r][c] = f2bf(WEb[idx]);
        s_weo[r][c] = f2bf(WEo[idx]);
    }
    __syncthreads();

    int wid = tid >> 6, lane = tid & 63;
    int lo5 = lane & 31, hi = lane >> 5;
    int mm = lane >> 4;
    int cc = (lane & 15) * 4;

    // Aw values matching this lane's A-fragment elements:
    // elem (ks,i) -> k = ks*16 + hi*4 + (i&3) + ((i>>2)<<3); Aw[d,h] = Aw[(k&7)*8 + (k>>3)]
    float awv[32];
    #pragma unroll
    for (int ks = 0; ks < 4; ++ks)
        #pragma unroll
        for (int i = 0; i < 8; ++i) {
            int k = ks * 16 + hi * 4 + (i & 3) + ((i >> 2) << 3);
            awv[ks * 8 + i] = Aw[(k & 7) * 8 + (k >> 3)];
        }
    float bEbn0 = bEb[lo5], bEbn1 = bEb[32 + lo5];
    float bEon0 = bEo[lo5], bEon1 = bEo[32 + lo5];

    for (int tile = blockIdx.x; tile < NTILES; tile += gridDim.x) {
        int e0 = tile * 128 + wid * 32;
        int pos = inv[e0 + lo5];

        // gather qk = Qh[dst]+Kh[src] -> s_cq[wid]  (coalesced float4, bf16)
        #pragma unroll
        for (int t = 0; t < 8; ++t) {
            int m = t * 4 + mm;
            int e = e0 + m;
            int dst = eidx[e], src = eidx[EE + e];
            float4 q = *(const float4*)(Qh + (size_t)dst * 64 + cc);
            float4 k = *(const float4*)(Kh + (size_t)src * 64 + cc);
            *(uint2*)&s_cq[wid][m][cc] = make_uint2(pack2(q.x + k.x, q.y + k.y),
                                                    pack2(q.z + k.z, q.w + k.w));
        }

        // eattr A-fragments
        short8 af[4];
        {
            const float* arow = eattr + (size_t)(e0 + lo5) * 64;
            #pragma unroll
            for (int ks = 0; ks < 4; ++ks) {
                int k0 = ks * 16 + hi * 4;
                float4 a0 = *(const float4*)(arow + k0);
                float4 a1 = *(const float4*)(arow + k0 + 8);
                U8 t;
                t.u[0] = make_uint2(pack2(a0.x, a0.y), pack2(a0.z, a0.w));
                t.u[1] = make_uint2(pack2(a1.x, a1.y), pack2(a1.z, a1.w));
                af[ks] = t.v;
            }
        }

        // Ew/Eb GEMM; epilogue reads qk and overwrites the same slot with conn
        #pragma unroll
        for (int nt = 0; nt < 2; ++nt) {
            int n = nt * 32 + lo5;
            f32x16 cEw = splat16(0.f), cEb = splat16(0.f);
            #pragma unroll
            for (int ks = 0; ks < 4; ++ks) {
                int k0 = ks * 16 + hi * 4;
                cEw = __builtin_amdgcn_mfma_f32_32x32x16_bf16(af[ks], ldsfrag(s_wew[n], k0), cEw, 0, 0, 0);
                cEb = __builtin_amdgcn_mfma_f32_32x32x16_bf16(af[ks], ldsfrag(s_web[n], k0), cEb, 0, 0, 0);
            }
            float bEbn = nt ? bEbn1 : bEbn0;
            #pragma unroll
            for (int r = 0; r < 16; ++r) {
                int m = (r & 3) + 8 * (r >> 2) + 4 * hi;
                float qk = bf2f(s_cq[wid][m][n]);
                float c1 = qk * cEw[r];
                float c2 = copysignf(sqrtf(fabsf(c1)), c1);
                s_cq[wid][m][n] = f2bf(c2 + cEb[r] + bEbn);
            }
        }

        // conn A-fragments
        short8 ca[4];
        #pragma unroll
        for (int ks = 0; ks < 4; ++ks) {
            int k0 = ks * 16 + hi * 4;
            ca[ks] = ldsfrag(s_cq[wid][lo5], k0);
        }

        // score on VALU: elem (ks,i) contributes to h = 2ks + (i>>2);
        // hi-halves hold complementary k -> one shfl_xor(32) completes the sum
        {
            float sc[8];
            #pragma unroll
            for (int h2 = 0; h2 < 8; ++h2) sc[h2] = 0.f;
            #pragma unroll
            for (int ks = 0; ks < 4; ++ks)
                #pragma unroll
                for (int i = 0; i < 8; ++i) {
                    float cv = bf2f((unsigned short)ca[ks][i]);
                    sc[2 * ks + (i >> 2)] = fmaf(cv, awv[ks * 8 + i], sc[2 * ks + (i >> 2)]);
                }
            #pragma unroll
            for (int h2 = 0; h2 < 8; ++h2) {
                sc[h2] += __shfl_xor(sc[h2], 32, 64);
                sc[h2] = fminf(fmaxf(sc[h2], -5.0f), 5.0f);
                sc[h2] = __expf(sc[h2]);
            }
            if (hi == 0) {   // CSR-ordered ex writes
                *(float4*)(exbuf + (size_t)pos * 8 + 0) = make_float4(sc[0], sc[1], sc[2], sc[3]);
                *(float4*)(exbuf + (size_t)pos * 8 + 4) = make_float4(sc[4], sc[5], sc[6], sc[7]);
            }
        }

        // Eo GEMM (+bias) -> output (e-ordered, coalesced)
        #pragma unroll
        for (int nt = 0; nt < 2; ++nt) {
            int n = nt * 32 + lo5;
            f32x16 cO = splat16(nt ? bEon1 : bEon0);
            #pragma unroll
            for (int ks = 0; ks < 4; ++ks) {
                int k0 = ks * 16 + hi * 4;
                cO = __builtin_amdgcn_mfma_f32_32x32x16_bf16(ca[ks], ldsfrag(s_weo[n], k0), cO, 0, 0, 0);
            }
            #pragma unroll
            for (int r = 0; r < 16; ++r) {
                int m = (r & 3) + 8 * (r >> 2) + 4 * hi;
                Eo_out[(size_t)(e0 + m) * 64 + n] = cO[r];
            }
        }
    }
}

// ---------------------------------------------------------------------------
// Kernel 3: node aggregation (CSR). One wave per node; lane = (h,d).
//   ex is CSR-ordered (sequential); 2-way unrolled accumulation.
// ---------------------------------------------------------------------------
__global__ __launch_bounds__(256) void node_kernel(
    const int* __restrict__ rowstart, const int* __restrict__ perm,
    const int* __restrict__ psrc,
    const float* __restrict__ exbuf, const float* __restrict__ Eo,
    const float* __restrict__ Vh, const float* __restrict__ BW,
    float* __restrict__ hout)
{
    int n = (blockIdx.x * blockDim.x + threadIdx.x) >> 6;
    int lane = threadIdx.x & 63;
    int h = lane >> 3, d = lane & 7;

    int beg = rowstart[n], end = rowstart[n + 1];
    float agg0 = 0.f, rv0 = 0.f, den0 = 0.f;
    float agg1 = 0.f, rv1 = 0.f, den1 = 0.f;
    int j = beg;
    for (; j + 1 < end; j += 2) {
        int ea = perm[j],     sa = psrc[j];
        int eb = perm[j + 1], sb = psrc[j + 1];
        float xa = exbuf[(size_t)j * 8 + h];
        float xb = exbuf[(size_t)(j + 1) * 8 + h];
        agg0 = fmaf(xa, Vh[(size_t)sa * 64 + lane], agg0);
        rv0  = fmaf(xa, Eo[(size_t)ea * 64 + lane], rv0);
        den0 += xa;
        agg1 = fmaf(xb, Vh[(size_t)sb * 64 + lane], agg1);
        rv1  = fmaf(xb, Eo[(size_t)eb * 64 + lane], rv1);
        den1 += xb;
    }
    if (j < end) {
        int ea = perm[j], sa = psrc[j];
        float xa = exbuf[(size_t)j * 8 + h];
        agg0 = fmaf(xa, Vh[(size_t)sa * 64 + lane], agg0);
        rv0  = fmaf(xa, Eo[(size_t)ea * 64 + lane], rv0);
        den0 += xa;
    }
    float agg = agg0 + agg1, rv = rv0 + rv1, den = den0 + den1;
    float inv = (den > 0.f) ? (1.0f / den) : 0.f;

    float acc = agg;
    #pragma unroll
    for (int dd = 0; dd < 8; ++dd) {
        float rvd = __shfl(rv, (h << 3) + dd, 64);
        acc = fmaf(rvd, BW[dd * 64 + (h << 3) + d], acc);
    }
    hout[(size_t)n * 64 + lane] = acc * inv;
}

// ---------------------------------------------------------------------------
extern "C" void kernel_launch(void* const* d_in, const int* in_sizes, int n_in,
                              void* d_out, int out_size, void* d_ws, size_t ws_size,
                              hipStream_t stream)
{
    const float* x    = (const float*)d_in[0];
    const float* ea   = (const float*)d_in[1];
    const int*   eidx = (const int*)  d_in[2];
    const float* WQ   = (const float*)d_in[3];
    const float* WK   = (const float*)d_in[4];
    const float* WV   = (const float*)d_in[5];
    const float* WEw  = (const float*)d_in[6];
    const float* WEb  = (const float*)d_in[7];
    const float* bEb  = (const float*)d_in[8];
    const float* WEo  = (const float*)d_in[9];
    const float* bEo  = (const float*)d_in[10];
    const float* Aw   = (const float*)d_in[11];
    const float* BW   = (const float*)d_in[12];

    float* hout   = (float*)d_out;
    float* Eo_out = hout + (size_t)NN * 64;

    float* Qh    = (float*)d_ws;
    float* Kh    = Qh + (size_t)NN * 64;
    float* Vh    = Kh + (size_t)NN * 64;
    float* exbuf = Vh + (size_t)NN * 64;
    int* cnt      = (int*)(exbuf + (size_t)EE * 8);  // doubles as cursor
    int* rowstart = cnt + NN;
    int* perm     = rowstart + (NN + 1);
    int* psrc     = perm + EE;
    int* invp     = psrc + EE;
    int* bsum     = invp + EE;
    int* boff     = bsum + 64;

    hipMemsetAsync(cnt, 0, (size_t)NN * sizeof(int), stream);

    hist_kernel<<<EE / 256, 256, 0, stream>>>(eidx, cnt);
    scan1_kernel<<<NB, 1024, 0, stream>>>(cnt, rowstart, bsum);
    scan2_kernel<<<1, 64, 0, stream>>>(bsum, boff, rowstart);
    scan3_kernel<<<NB, 1024, 0, stream>>>(rowstart, boff, cnt);
    scatter_kernel<<<EE / 256, 256, 0, stream>>>(eidx, cnt, perm, psrc, invp);

    qkv_mfma_kernel<<<(NN + 127) / 128, 256, 0, stream>>>(x, WQ, WK, WV, Qh, Kh, Vh);

    edge_mfma_kernel<<<2080, 256, 0, stream>>>(ea, eidx, invp, WEw, WEb, bEb, WEo, bEo, Aw,
                                               Qh, Kh, Eo_out, exbuf);

    node_kernel<<<(NN * 64) / 256, 256, 0, stream>>>(rowstart, perm, psrc,
                                                     exbuf, Eo_out, Vh, BW, hout);
}